// Round 8
// baseline (513.905 us; speedup 1.0000x reference)
//
#include <hip/hip_runtime.h>
#include <math.h>

using bh8    = __attribute__((ext_vector_type(8))) short;   // 8 x bf16
using f32x16 = __attribute__((ext_vector_type(16))) float;
typedef unsigned int u32;

#define NN   1152
#define CCAP 32
#define DI   16
#define DCAP 32
#define TNR  9          // n's per route block
#define NTILES 128      // 1152/9
#define CAPS_EPS 1e-7f

// workspace layout (bytes)
#define WS_WB    0ul          // 37,748,736  bf16 W frags [n][c][l][8]
#define WS_XB    37748736ul   //  2,359,296  bf16 x frags [h][n][l][8]
#define WS_PART  40108032ul   // 33,554,432  partial s [bk][c][l][16r] f32
#define WS_PART2 73662464ul   //  4,194,304  stage-2 partials
#define WS_OPK   77856768ul   //    131,072  out frags bf16 [h][c][plane][l][4w]
#define WS_BLOG  77987840ul   //  9,437,184  logits [n][c][h][b32]

__device__ __forceinline__ short f2bf(float f) {
    u32 u = __float_as_uint(f);
    u += 0x7fffu + ((u >> 16) & 1u);   // round-to-nearest-even
    return (short)(u >> 16);
}

__device__ __forceinline__ void gld_lds16(const void* g, void* s) {
    __builtin_amdgcn_global_load_lds(
        (const __attribute__((address_space(1))) u32*)g,
        (__attribute__((address_space(3))) u32*)s, 16, 0, 0);
}

// ---------------------------------------------------------------------------
// W[c][n][j][i] f32 -> Wb[n][c][l] bf16 A-frag chunks: lane l holds
// W[c, n, j=l&31, i = 8*(l>>5) .. +7].  Coalesced 16B writes.
// ---------------------------------------------------------------------------
__global__ __launch_bounds__(256)
void conv_w(const float* __restrict__ W, short* __restrict__ Wb)
{
    const int m = blockIdx.x * 256 + threadIdx.x;   // (n*32+c)*64+l
    const int l = m & 63, c = (m >> 6) & 31, n = m >> 11;
    const int j = l & 31, hi = l >> 5;
    const float* src = W + (((size_t)c * NN + n) * DCAP + j) * DI + hi * 8;
    const float4 a = ((const float4*)src)[0];
    const float4 b = ((const float4*)src)[1];
    bh8 r;
    r[0] = f2bf(a.x); r[1] = f2bf(a.y); r[2] = f2bf(a.z); r[3] = f2bf(a.w);
    r[4] = f2bf(b.x); r[5] = f2bf(b.y); r[6] = f2bf(b.z); r[7] = f2bf(b.w);
    *(bh8*)(Wb + (size_t)m * 8) = r;
}

// x[b][n][i] f32 -> xb[h][n][l] bf16 B-frag chunks: lane l holds
// x[b = h*32+(l&31), n, i = 8*(l>>5) .. +7].
__global__ __launch_bounds__(256)
void conv_x(const float* __restrict__ X, short* __restrict__ xb)
{
    const int m = blockIdx.x * 256 + threadIdx.x;   // (h*1152+n)*64+l
    const int l = m & 63;
    const int h = m / (NN * 64);
    const int n = (m >> 6) % NN;
    const int b = h * 32 + (l & 31), hi = l >> 5;
    const float* src = X + ((size_t)b * NN + n) * DI + hi * 8;
    const float4 a = ((const float4*)src)[0];
    const float4 c4 = ((const float4*)src)[1];
    bh8 r;
    r[0] = f2bf(a.x);  r[1] = f2bf(a.y);  r[2] = f2bf(a.z);  r[3] = f2bf(a.w);
    r[4] = f2bf(c4.x); r[5] = f2bf(c4.y); r[6] = f2bf(c4.z); r[7] = f2bf(c4.w);
    *(bh8*)(xb + (size_t)m * 8) = r;
}

// ---------------------------------------------------------------------------
// One routing iteration. Block: 1024 thr = 16 waves x 2 c each; covers b-half
// h, all 32 c, TNR=9 n's. W frags come straight from global (coalesced 16B
// per lane, register-prefetched one n ahead) — no W LDS, no vmcnt-drain
// coupling to the softmax barriers. VGPR capped at 128 -> 16 waves/CU.
// ---------------------------------------------------------------------------
template<int T>
__global__ __launch_bounds__(1024, 4)
void route_k(const short* __restrict__ Wb, const short* __restrict__ xb,
             const u32* __restrict__ opk, float* __restrict__ blog,
             float* __restrict__ part)
{
    __shared__ __align__(16) char Xl[TNR * 1024];   // x frags [n][l][16B]
    __shared__ float DU[CCAP * 33];
    __shared__ float CF[CCAP * 33];

    const int tid = threadIdx.x;
    const int w = tid >> 6, l = tid & 63, bl31 = l & 31;
    const int nt = blockIdx.x, h = blockIdx.y;
    const int n0 = nt * TNR;
    const int bk = h * NTILES + nt;
    const int c0 = w * 2, c1 = c0 + 1;

    // stage x frags (9216 B): waves 0..8, 16B per lane, linear dest
    if (tid < TNR * 64) {
        const char* xs = (const char*)(xb + ((size_t)h * NN + n0) * 512);
        gld_lds16(xs + tid * 16, Xl + tid * 16);
    }

    // prev-output bf16 frags -> registers (n-invariant)
    uint4 opr[2][2];
    if (T > 0) {
        const char* ob = (const char*)opk;
        opr[0][0] = *(const uint4*)(ob + ((((size_t)h * CCAP + c0) * 2 + 0) * 64 + l) * 16);
        opr[0][1] = *(const uint4*)(ob + ((((size_t)h * CCAP + c0) * 2 + 1) * 64 + l) * 16);
        opr[1][0] = *(const uint4*)(ob + ((((size_t)h * CCAP + c1) * 2 + 0) * 64 + l) * 16);
        opr[1][1] = *(const uint4*)(ob + ((((size_t)h * CCAP + c1) * 2 + 1) * 64 + l) * 16);
    }

    // first W fragments (prefetch chain start)
    bh8 wA0, wA1, wB0, wB1;
    {
        const short* p = Wb + (size_t)n0 * 16384;
        wA0 = *(const bh8*)(p + (c0 * 64 + l) * 8);
        wA1 = *(const bh8*)(p + (c1 * 64 + l) * 8);
    }

    f32x16 s0, s1;
#pragma unroll
    for (int r = 0; r < 16; ++r) { s0[r] = 0.f; s1[r] = 0.f; }

    __syncthreads();   // Xl ready

#pragma unroll
    for (int n = 0; n < TNR; ++n) {
        const int na = n0 + n;

        if (n + 1 < TNR) {   // register prefetch of next n's W frags
            const short* p = Wb + (size_t)(na + 1) * 16384;
            wB0 = *(const bh8*)(p + (c0 * 64 + l) * 8);
            wB1 = *(const bh8*)(p + (c1 * 64 + l) * 8);
        }

        const bh8 xf = *(const bh8*)(Xl + n * 1024 + l * 16);

        if (T == 0) {
            // coef uniform: s = (1/32) sum_n u_hat (1/32 applied in reduce2)
            s0 = __builtin_amdgcn_mfma_f32_32x32x16_bf16(wA0, xf, s0, 0, 0, 0);
            s1 = __builtin_amdgcn_mfma_f32_32x32x16_bf16(wA1, xf, s1, 0, 0, 0);
        } else {
            f32x16 zz;
#pragma unroll
            for (int r = 0; r < 16; ++r) zz[r] = 0.f;
            f32x16 u0 = __builtin_amdgcn_mfma_f32_32x32x16_bf16(wA0, xf, zz, 0, 0, 0);
            f32x16 u1 = __builtin_amdgcn_mfma_f32_32x32x16_bf16(wA1, xf, zz, 0, 0, 0);

            // du[b] = dot(out_prev[b,c,:], u_hatT[:,b]) — lane-local 16 j's
            float d0 = 0.f, d1 = 0.f;
#pragma unroll
            for (int p = 0; p < 8; ++p) {
                const u32 o0 = (p < 4) ? (&opr[0][0].x)[p] : (&opr[0][1].x)[p - 4];
                const u32 o1 = (p < 4) ? (&opr[1][0].x)[p] : (&opr[1][1].x)[p - 4];
                d0 = fmaf(__uint_as_float(o0 << 16),        u0[2 * p + 0], d0);
                d0 = fmaf(__uint_as_float(o0 & 0xffff0000u), u0[2 * p + 1], d0);
                d1 = fmaf(__uint_as_float(o1 << 16),        u1[2 * p + 0], d1);
                d1 = fmaf(__uint_as_float(o1 & 0xffff0000u), u1[2 * p + 1], d1);
            }
            d0 += __shfl_xor(d0, 32);   // partner j-half
            d1 += __shfl_xor(d1, 32);
            if (T == 2) {
                d0 += blog[(((size_t)na * CCAP + c0) * 2 + h) * 32 + bl31];
                d1 += blog[(((size_t)na * CCAP + c1) * 2 + h) * 32 + bl31];
            }
            if (l < 32) {
                DU[c0 * 33 + l] = d0;
                DU[c1 * 33 + l] = d1;
                if (T == 1) {
                    blog[(((size_t)na * CCAP + c0) * 2 + h) * 32 + l] = d0;
                    blog[(((size_t)na * CCAP + c1) * 2 + h) * 32 + l] = d1;
                }
            }
            __syncthreads();

            // softmax over c for each b: threads 0..511, (b = t>>4, g = t&15)
            if (tid < 512) {
                const int b = tid >> 4, g = tid & 15;
                const float v0 = DU[g * 33 + b], v1 = DU[(g + 16) * 33 + b];
                float m = fmaxf(v0, v1);
#pragma unroll
                for (int d2 = 1; d2 < 16; d2 <<= 1) m = fmaxf(m, __shfl_xor(m, d2));
                const float e0 = __expf(v0 - m), e1 = __expf(v1 - m);
                float es = e0 + e1;
#pragma unroll
                for (int d2 = 1; d2 < 16; d2 <<= 1) es += __shfl_xor(es, d2);
                const float inv = 1.0f / es;
                CF[g * 33 + b] = e0 * inv;
                CF[(g + 16) * 33 + b] = e1 * inv;
            }
            __syncthreads();

            const float cf0 = CF[c0 * 33 + bl31];
            const float cf1 = CF[c1 * 33 + bl31];
#pragma unroll
            for (int r = 0; r < 16; ++r) {
                s0[r] = fmaf(cf0, u0[r], s0[r]);
                s1[r] = fmaf(cf1, u1[r], s1[r]);
            }
        }
        wA0 = wB0; wA1 = wB1;
    }

    // write partial s in frag layout [bk][c][l][16r], coalesced dwordx4
    {
        float* dst0 = part + (((size_t)bk * CCAP + c0) * 64 + l) * 16;
        float* dst1 = part + (((size_t)bk * CCAP + c1) * 64 + l) * 16;
#pragma unroll
        for (int k = 0; k < 4; ++k) {
            float4 v0, v1;
            v0.x = s0[4 * k]; v0.y = s0[4 * k + 1]; v0.z = s0[4 * k + 2]; v0.w = s0[4 * k + 3];
            v1.x = s1[4 * k]; v1.y = s1[4 * k + 1]; v1.z = s1[4 * k + 2]; v1.w = s1[4 * k + 3];
            ((float4*)dst0)[k] = v0;
            ((float4*)dst1)[k] = v1;
        }
    }
}

// ---------------------------------------------------------------------------
// Stage-1 reduce: sum 8 n-tiles per block. grid (ch=16, c=32, h=2).
// ---------------------------------------------------------------------------
__global__ __launch_bounds__(1024)
void reduce1_k(const float* __restrict__ part, float* __restrict__ part2)
{
    const int t = threadIdx.x;
    const int ch = blockIdx.x, c = blockIdx.y, h = blockIdx.z;
    float a = 0.f;
#pragma unroll
    for (int s = 0; s < 8; ++s) {
        const int nt = ch * 8 + s;
        a += part[((size_t)(h * NTILES + nt) * CCAP + c) * 1024 + t];
    }
    part2[(((size_t)h * CCAP + c) * 16 + ch) * 1024 + t] = a;
}

// ---------------------------------------------------------------------------
// Stage-2: final sum + squash. grid (c=32, h=2). t -> (l = t>>4, r = t&15).
// FIN=0: writes bf16 out-frags (for next route's du). FIN=1: writes d_out.
// ---------------------------------------------------------------------------
template<int FIN>
__global__ __launch_bounds__(1024)
void reduce2_k(const float* __restrict__ part2, u32* __restrict__ opk,
               float* __restrict__ outp, float sc0)
{
    const int t = threadIdx.x;
    const int c = blockIdx.x, h = blockIdx.y;
    const int l = t >> 4, r = t & 15;
    float s = 0.f;
#pragma unroll
    for (int ch = 0; ch < 16; ++ch)
        s += part2[(((size_t)h * CCAP + c) * 16 + ch) * 1024 + t];
    s *= sc0;

    float q = s * s;
    q += __shfl_xor(q, 1); q += __shfl_xor(q, 2);
    q += __shfl_xor(q, 4); q += __shfl_xor(q, 8);
    __shared__ float ssq[64], scl[32];
    if (r == 0) ssq[l] = q;
    __syncthreads();
    if (t < 32) {
        const float v = ssq[t] + ssq[t + 32];
        scl[t] = v / ((1.0f + v) * sqrtf(v + CAPS_EPS));
    }
    __syncthreads();
    const float o = s * scl[l & 31];

    if (FIN) {
        const int b = h * 32 + (l & 31);
        const int j = (r & 3) + 8 * (r >> 2) + 4 * (l >> 5);
        outp[((size_t)b * CCAP + c) * DCAP + j] = o;
    } else {
        const float o1 = __shfl_xor(o, 1);
        if (!(r & 1)) {
            const u32 pk = (u32)(unsigned short)f2bf(o) |
                           ((u32)(unsigned short)f2bf(o1) << 16);
            opk[((((size_t)h * CCAP + c) * 2 + (r >> 3)) * 64 + l) * 4 + ((r >> 1) & 3)] = pk;
        }
    }
}

extern "C" void kernel_launch(void* const* d_in, const int* in_sizes, int n_in,
                              void* d_out, int out_size, void* d_ws, size_t ws_size,
                              hipStream_t stream)
{
    const float* inp = (const float*)d_in[0];   // [B, N, Di]
    const float* Wt  = (const float*)d_in[1];   // [C, N, Dc, Di]
    float* out = (float*)d_out;                 // [B, C, Dc]

    char* ws = (char*)d_ws;
    short* Wb    = (short*)(ws + WS_WB);
    short* xb    = (short*)(ws + WS_XB);
    float* part  = (float*)(ws + WS_PART);
    float* part2 = (float*)(ws + WS_PART2);
    u32*   opk   = (u32*)  (ws + WS_OPK);
    float* blog  = (float*)(ws + WS_BLOG);

    conv_w<<<9216, 256, 0, stream>>>(Wt, Wb);
    conv_x<<<576, 256, 0, stream>>>(inp, xb);

    const dim3 gr(NTILES, 2), br(1024);
    const dim3 g1(16, 32, 2);
    const dim3 g2(32, 2);

    route_k<0><<<gr, br, 0, stream>>>(Wb, xb, opk, blog, part);
    reduce1_k<<<g1, 1024, 0, stream>>>(part, part2);
    reduce2_k<0><<<g2, 1024, 0, stream>>>(part2, opk, out, 1.0f / 32.0f);

    route_k<1><<<gr, br, 0, stream>>>(Wb, xb, opk, blog, part);
    reduce1_k<<<g1, 1024, 0, stream>>>(part, part2);
    reduce2_k<0><<<g2, 1024, 0, stream>>>(part2, opk, out, 1.0f);

    route_k<2><<<gr, br, 0, stream>>>(Wb, xb, opk, blog, part);
    reduce1_k<<<g1, 1024, 0, stream>>>(part, part2);
    reduce2_k<1><<<g2, 1024, 0, stream>>>(part2, opk, out, 1.0f);
}

// Round 9
// 482.021 us; speedup vs baseline: 1.0661x; 1.0661x over previous
//
#include <hip/hip_runtime.h>
#include <math.h>

using bh8    = __attribute__((ext_vector_type(8))) short;   // 8 x bf16
using f32x16 = __attribute__((ext_vector_type(16))) float;
typedef unsigned int u32;

#define NN   1152
#define CCAP 32
#define DI   16
#define DCAP 32
#define TNR  9          // n's per route block
#define NTILES 128      // 1152/9
#define CAPS_EPS 1e-7f

// workspace layout (bytes)
#define WS_WB    0ul          // 37,748,736  bf16 W frags [n][c][l][8]
#define WS_XB    37748736ul   //  2,359,296  bf16 x frags [h][n][l][8]
#define WS_PART  40108032ul   // 33,554,432  partial s [bk][c][l][16r] f32
#define WS_PART2 73662464ul   //  4,194,304  stage-2 partials
#define WS_OPK   77856768ul   //    131,072  out frags bf16 [h][c][plane][l][4w]
#define WS_BLOG  77987840ul   //  9,437,184  logits [n][c][h][b32]

__device__ __forceinline__ short f2bf(float f) {
    u32 u = __float_as_uint(f);
    u += 0x7fffu + ((u >> 16) & 1u);   // round-to-nearest-even
    return (short)(u >> 16);
}

__device__ __forceinline__ void gld_lds16(const void* g, void* s) {
    __builtin_amdgcn_global_load_lds(
        (const __attribute__((address_space(1))) u32*)g,
        (__attribute__((address_space(3))) u32*)s, 16, 0, 0);
}

// ---------------------------------------------------------------------------
// Fused input conversion (one launch).
// blocks [0, 9216):  W[c][n][j][i] f32 -> Wb[n][c][l] bf16 A-frags:
//   lane l holds W[c, n, j=l&31, i=8*(l>>5)..+7].
// blocks [9216, 9792): x[b][n][i] f32 -> xb[h][n][l] bf16 B-frags:
//   lane l holds x[b=h*32+(l&31), n, i=8*(l>>5)..+7].
// ---------------------------------------------------------------------------
__global__ __launch_bounds__(256)
void conv_wx(const float* __restrict__ W, const float* __restrict__ X,
             short* __restrict__ Wb, short* __restrict__ xb)
{
    const int bid = blockIdx.x;
    if (bid < 9216) {
        const int m = bid * 256 + threadIdx.x;   // (n*32+c)*64+l
        const int l = m & 63, c = (m >> 6) & 31, n = m >> 11;
        const int j = l & 31, hi = l >> 5;
        const float* src = W + (((size_t)c * NN + n) * DCAP + j) * DI + hi * 8;
        const float4 a = ((const float4*)src)[0];
        const float4 b = ((const float4*)src)[1];
        bh8 r;
        r[0] = f2bf(a.x); r[1] = f2bf(a.y); r[2] = f2bf(a.z); r[3] = f2bf(a.w);
        r[4] = f2bf(b.x); r[5] = f2bf(b.y); r[6] = f2bf(b.z); r[7] = f2bf(b.w);
        *(bh8*)(Wb + (size_t)m * 8) = r;
    } else {
        const int m = (bid - 9216) * 256 + threadIdx.x;   // (h*1152+n)*64+l
        const int l = m & 63;
        const int h = m / (NN * 64);
        const int n = (m >> 6) % NN;
        const int b = h * 32 + (l & 31), hi = l >> 5;
        const float* src = X + ((size_t)b * NN + n) * DI + hi * 8;
        const float4 a = ((const float4*)src)[0];
        const float4 c4 = ((const float4*)src)[1];
        bh8 r;
        r[0] = f2bf(a.x);  r[1] = f2bf(a.y);  r[2] = f2bf(a.z);  r[3] = f2bf(a.w);
        r[4] = f2bf(c4.x); r[5] = f2bf(c4.y); r[6] = f2bf(c4.z); r[7] = f2bf(c4.w);
        *(bh8*)(xb + (size_t)m * 8) = r;
    }
}

// ---------------------------------------------------------------------------
// One routing iteration. Block: 1024 thr = 16 waves x 2 c each; covers b-half
// h, all 32 c, TNR=9 n's. W frags straight from global (coalesced 16B/lane,
// one-deep register prefetch). Register discipline: u_hat is computed
// TRANSIENTLY for the du-dot (dies before the barrier) and RECOMPUTED by a
// second identical MFMA after softmax (bit-identical, MFMA is ~free at 0.5%
// util) — nothing but sacc+opr+wA/wB lives across the barriers, so we fit
// the natural 128-VGPR cap of a 1024-thread block without spilling.
// ---------------------------------------------------------------------------
template<int T>
__global__ __launch_bounds__(1024)
void route_k(const short* __restrict__ Wb, const short* __restrict__ xb,
             const u32* __restrict__ opk, float* __restrict__ blog,
             float* __restrict__ part)
{
    __shared__ __align__(16) char Xl[TNR * 1024];   // x frags [n][l][16B]
    __shared__ float DU[CCAP * 33];
    __shared__ float CF[CCAP * 33];

    const int tid = threadIdx.x;
    const int w = tid >> 6, l = tid & 63, bl31 = l & 31;
    const int nt = blockIdx.x, h = blockIdx.y;
    const int n0 = nt * TNR;
    const int bk = h * NTILES + nt;
    const int c0 = w * 2, c1 = c0 + 1;

    // stage x frags (9216 B): waves 0..8, 16B per lane, linear dest
    if (tid < TNR * 64) {
        const char* xs = (const char*)(xb + ((size_t)h * NN + n0) * 512);
        gld_lds16(xs + tid * 16, Xl + tid * 16);
    }

    // prev-output bf16 frags -> registers (n-invariant)
    uint4 opr[2][2];
    if (T > 0) {
        const char* ob = (const char*)opk;
        opr[0][0] = *(const uint4*)(ob + ((((size_t)h * CCAP + c0) * 2 + 0) * 64 + l) * 16);
        opr[0][1] = *(const uint4*)(ob + ((((size_t)h * CCAP + c0) * 2 + 1) * 64 + l) * 16);
        opr[1][0] = *(const uint4*)(ob + ((((size_t)h * CCAP + c1) * 2 + 0) * 64 + l) * 16);
        opr[1][1] = *(const uint4*)(ob + ((((size_t)h * CCAP + c1) * 2 + 1) * 64 + l) * 16);
    }

    // first W fragments (prefetch chain start)
    bh8 wA0, wA1, wB0, wB1;
    {
        const short* p = Wb + (size_t)n0 * 16384;
        wA0 = *(const bh8*)(p + (c0 * 64 + l) * 8);
        wA1 = *(const bh8*)(p + (c1 * 64 + l) * 8);
    }

    f32x16 s0, s1;
#pragma unroll
    for (int r = 0; r < 16; ++r) { s0[r] = 0.f; s1[r] = 0.f; }

    __syncthreads();   // Xl ready

#pragma unroll
    for (int n = 0; n < TNR; ++n) {
        const int na = n0 + n;

        if (n + 1 < TNR) {   // register prefetch of next n's W frags
            const short* p = Wb + (size_t)(na + 1) * 16384;
            wB0 = *(const bh8*)(p + (c0 * 64 + l) * 8);
            wB1 = *(const bh8*)(p + (c1 * 64 + l) * 8);
        }

        const bh8 xf = *(const bh8*)(Xl + n * 1024 + l * 16);

        if (T == 0) {
            // coef uniform: s = (1/32) sum_n u_hat (1/32 applied in reduce2)
            s0 = __builtin_amdgcn_mfma_f32_32x32x16_bf16(wA0, xf, s0, 0, 0, 0);
            s1 = __builtin_amdgcn_mfma_f32_32x32x16_bf16(wA1, xf, s1, 0, 0, 0);
        } else {
            f32x16 zz;
#pragma unroll
            for (int r = 0; r < 16; ++r) zz[r] = 0.f;

            // --- du pass: u_hat transient, dies before the barrier ---
            float d0, d1;
            {
                const f32x16 ut = __builtin_amdgcn_mfma_f32_32x32x16_bf16(wA0, xf, zz, 0, 0, 0);
                float d = 0.f;
#pragma unroll
                for (int p = 0; p < 8; ++p) {
                    const u32 o = (p < 4) ? (&opr[0][0].x)[p] : (&opr[0][1].x)[p - 4];
                    d = fmaf(__uint_as_float(o << 16),         ut[2 * p + 0], d);
                    d = fmaf(__uint_as_float(o & 0xffff0000u), ut[2 * p + 1], d);
                }
                d0 = d;
            }
            {
                const f32x16 ut = __builtin_amdgcn_mfma_f32_32x32x16_bf16(wA1, xf, zz, 0, 0, 0);
                float d = 0.f;
#pragma unroll
                for (int p = 0; p < 8; ++p) {
                    const u32 o = (p < 4) ? (&opr[1][0].x)[p] : (&opr[1][1].x)[p - 4];
                    d = fmaf(__uint_as_float(o << 16),         ut[2 * p + 0], d);
                    d = fmaf(__uint_as_float(o & 0xffff0000u), ut[2 * p + 1], d);
                }
                d1 = d;
            }
            d0 += __shfl_xor(d0, 32);   // partner j-half
            d1 += __shfl_xor(d1, 32);
            if (T == 2) {
                d0 += blog[(((size_t)na * CCAP + c0) * 2 + h) * 32 + bl31];
                d1 += blog[(((size_t)na * CCAP + c1) * 2 + h) * 32 + bl31];
            }
            if (l < 32) {
                DU[c0 * 33 + l] = d0;
                DU[c1 * 33 + l] = d1;
                if (T == 1) {
                    blog[(((size_t)na * CCAP + c0) * 2 + h) * 32 + l] = d0;
                    blog[(((size_t)na * CCAP + c1) * 2 + h) * 32 + l] = d1;
                }
            }
            __syncthreads();

            // softmax over c for each b: threads 0..511, (b = t>>4, g = t&15)
            if (tid < 512) {
                const int b = tid >> 4, g = tid & 15;
                const float v0 = DU[g * 33 + b], v1 = DU[(g + 16) * 33 + b];
                float m = fmaxf(v0, v1);
#pragma unroll
                for (int d2 = 1; d2 < 16; d2 <<= 1) m = fmaxf(m, __shfl_xor(m, d2));
                const float e0 = __expf(v0 - m), e1 = __expf(v1 - m);
                float es = e0 + e1;
#pragma unroll
                for (int d2 = 1; d2 < 16; d2 <<= 1) es += __shfl_xor(es, d2);
                const float inv = 1.0f / es;
                CF[g * 33 + b] = e0 * inv;
                CF[(g + 16) * 33 + b] = e1 * inv;
            }
            __syncthreads();
            // keep the recompute MFMAs BELOW the barrier (don't let the
            // scheduler hoist them up and extend u's live range)
            __builtin_amdgcn_sched_barrier(0);

            const float cf0 = CF[c0 * 33 + bl31];
            const float cf1 = CF[c1 * 33 + bl31];
            {
                const f32x16 ut = __builtin_amdgcn_mfma_f32_32x32x16_bf16(wA0, xf, zz, 0, 0, 0);
#pragma unroll
                for (int r = 0; r < 16; ++r) s0[r] = fmaf(cf0, ut[r], s0[r]);
            }
            {
                const f32x16 ut = __builtin_amdgcn_mfma_f32_32x32x16_bf16(wA1, xf, zz, 0, 0, 0);
#pragma unroll
                for (int r = 0; r < 16; ++r) s1[r] = fmaf(cf1, ut[r], s1[r]);
            }
        }
        wA0 = wB0; wA1 = wB1;
    }

    // write partial s in frag layout [bk][c][l][16r], coalesced dwordx4
    {
        float* dst0 = part + (((size_t)bk * CCAP + c0) * 64 + l) * 16;
        float* dst1 = part + (((size_t)bk * CCAP + c1) * 64 + l) * 16;
#pragma unroll
        for (int k = 0; k < 4; ++k) {
            float4 v0, v1;
            v0.x = s0[4 * k]; v0.y = s0[4 * k + 1]; v0.z = s0[4 * k + 2]; v0.w = s0[4 * k + 3];
            v1.x = s1[4 * k]; v1.y = s1[4 * k + 1]; v1.z = s1[4 * k + 2]; v1.w = s1[4 * k + 3];
            ((float4*)dst0)[k] = v0;
            ((float4*)dst1)[k] = v1;
        }
    }
}

// ---------------------------------------------------------------------------
// Stage-1 reduce: sum 8 n-tiles per block. grid (ch=16, c=32, h=2).
// ---------------------------------------------------------------------------
__global__ __launch_bounds__(1024)
void reduce1_k(const float* __restrict__ part, float* __restrict__ part2)
{
    const int t = threadIdx.x;
    const int ch = blockIdx.x, c = blockIdx.y, h = blockIdx.z;
    float a = 0.f;
#pragma unroll
    for (int s = 0; s < 8; ++s) {
        const int nt = ch * 8 + s;
        a += part[((size_t)(h * NTILES + nt) * CCAP + c) * 1024 + t];
    }
    part2[(((size_t)h * CCAP + c) * 16 + ch) * 1024 + t] = a;
}

// ---------------------------------------------------------------------------
// Stage-2: final sum + squash. grid (c=32, h=2). t -> (l = t>>4, r = t&15).
// FIN=0: writes bf16 out-frags (for next route's du). FIN=1: writes d_out.
// ---------------------------------------------------------------------------
template<int FIN>
__global__ __launch_bounds__(1024)
void reduce2_k(const float* __restrict__ part2, u32* __restrict__ opk,
               float* __restrict__ outp, float sc0)
{
    const int t = threadIdx.x;
    const int c = blockIdx.x, h = blockIdx.y;
    const int l = t >> 4, r = t & 15;
    float s = 0.f;
#pragma unroll
    for (int ch = 0; ch < 16; ++ch)
        s += part2[(((size_t)h * CCAP + c) * 16 + ch) * 1024 + t];
    s *= sc0;

    float q = s * s;
    q += __shfl_xor(q, 1); q += __shfl_xor(q, 2);
    q += __shfl_xor(q, 4); q += __shfl_xor(q, 8);
    __shared__ float ssq[64], scl[32];
    if (r == 0) ssq[l] = q;
    __syncthreads();
    if (t < 32) {
        const float v = ssq[t] + ssq[t + 32];
        scl[t] = v / ((1.0f + v) * sqrtf(v + CAPS_EPS));
    }
    __syncthreads();
    const float o = s * scl[l & 31];

    if (FIN) {
        const int b = h * 32 + (l & 31);
        const int j = (r & 3) + 8 * (r >> 2) + 4 * (l >> 5);
        outp[((size_t)b * CCAP + c) * DCAP + j] = o;
    } else {
        const float o1 = __shfl_xor(o, 1);
        if (!(r & 1)) {
            const u32 pk = (u32)(unsigned short)f2bf(o) |
                           ((u32)(unsigned short)f2bf(o1) << 16);
            opk[((((size_t)h * CCAP + c) * 2 + (r >> 3)) * 64 + l) * 4 + ((r >> 1) & 3)] = pk;
        }
    }
}

extern "C" void kernel_launch(void* const* d_in, const int* in_sizes, int n_in,
                              void* d_out, int out_size, void* d_ws, size_t ws_size,
                              hipStream_t stream)
{
    const float* inp = (const float*)d_in[0];   // [B, N, Di]
    const float* Wt  = (const float*)d_in[1];   // [C, N, Dc, Di]
    float* out = (float*)d_out;                 // [B, C, Dc]

    char* ws = (char*)d_ws;
    short* Wb    = (short*)(ws + WS_WB);
    short* xb    = (short*)(ws + WS_XB);
    float* part  = (float*)(ws + WS_PART);
    float* part2 = (float*)(ws + WS_PART2);
    u32*   opk   = (u32*)  (ws + WS_OPK);
    float* blog  = (float*)(ws + WS_BLOG);

    conv_wx<<<9792, 256, 0, stream>>>(Wt, inp, Wb, xb);

    const dim3 gr(NTILES, 2), br(1024);
    const dim3 g1(16, 32, 2);
    const dim3 g2(32, 2);

    route_k<0><<<gr, br, 0, stream>>>(Wb, xb, opk, blog, part);
    reduce1_k<<<g1, 1024, 0, stream>>>(part, part2);
    reduce2_k<0><<<g2, 1024, 0, stream>>>(part2, opk, out, 1.0f / 32.0f);

    route_k<1><<<gr, br, 0, stream>>>(Wb, xb, opk, blog, part);
    reduce1_k<<<g1, 1024, 0, stream>>>(part, part2);
    reduce2_k<0><<<g2, 1024, 0, stream>>>(part2, opk, out, 1.0f);

    route_k<2><<<gr, br, 0, stream>>>(Wb, xb, opk, blog, part);
    reduce1_k<<<g1, 1024, 0, stream>>>(part, part2);
    reduce2_k<1><<<g2, 1024, 0, stream>>>(part2, opk, out, 1.0f);
}